// Round 5
// baseline (870.782 us; speedup 1.0000x reference)
//
#include <hip/hip_runtime.h>

// Problem constants (from reference).
constexpr int E  = 640000;   // edges (= 2500 * 256 exactly)
constexpr int H  = 128;      // hidden
constexpr int P  = 16;       // pair dim
constexpr int NN = 50000;    // nodes
constexpr int OE = 256;      // out emb

// ws layout (bytes): cnt (NN+1 ints, becomes offs after scan) | cursor | eid
constexpr size_t OFF_CNT    = 0;
constexpr size_t OFF_CURSOR = 200192;
constexpr size_t OFF_EID    = 400384;   // + E*4 = 2,960,384 bytes total

__device__ __forceinline__ float silu(float v) {
    return v / (1.f + __expf(-v));
}

// ---------------------------------------------------------------------------
// Per-wave idx dtype detection. Reads only words 1..255 (safe in both
// layouts). int32 random indices: odd words ~never all zero. little-endian
// int64 (<2^31): odd words all zero. P(misdetect) ~ (2e-5)^128.
// ---------------------------------------------------------------------------
__device__ __forceinline__ bool idx_is_i64(const void* idxraw) {
    const unsigned* u = (const unsigned*)idxraw;
    const int lane = threadIdx.x & 63;
    const unsigned v = u[2 * lane + 1] | u[2 * lane + 129];
    return !__any(v != 0);
}

__device__ __forceinline__ int load_idx(const void* idxraw, bool i64, int e) {
    return i64 ? (int)((const long long*)idxraw)[e]
               : ((const int*)idxraw)[e];
}

// ---------------------------------------------------------------------------
// Kernel 1: histogram of node indices. One edge per thread (E%256==0).
// ---------------------------------------------------------------------------
__global__ __launch_bounds__(256) void hist_kernel(
    const void* __restrict__ idxraw, int* __restrict__ cnt)
{
    const bool i64 = idx_is_i64(idxraw);
    const int e = blockIdx.x * 256 + threadIdx.x;
    atomicAdd(&cnt[load_idx(idxraw, i64, e)], 1);
}

// ---------------------------------------------------------------------------
// Kernel 2: exclusive scan of cnt[0..NN) in place (-> offsets), copy to
// cursor, sentinel cnt[NN]=E. Single block, 1024 threads, chunk=49.
// ---------------------------------------------------------------------------
__global__ __launch_bounds__(1024) void scan_kernel(
    int* __restrict__ cnt, int* __restrict__ cursor)
{
    __shared__ int ssum[1024];
    const int t  = threadIdx.x;
    const int lo = t * 49;
    const int hi = min(lo + 49, NN);

    int s = 0;
    for (int i = lo; i < hi; ++i) s += cnt[i];
    ssum[t] = s;
    __syncthreads();
    for (int d = 1; d < 1024; d <<= 1) {
        const int v = (t >= d) ? ssum[t - d] : 0;
        __syncthreads();
        ssum[t] += v;
        __syncthreads();
    }
    int run = ssum[t] - s;          // exclusive prefix of this chunk
    for (int i = lo; i < hi; ++i) {
        const int c = cnt[i];
        cnt[i] = run;
        cursor[i] = run;
        run += c;
    }
    if (t == 0) cnt[NN] = E;
}

// ---------------------------------------------------------------------------
// Kernel 3: fill CSR edge-id list. One edge per thread.
// ---------------------------------------------------------------------------
__global__ __launch_bounds__(256) void fill_kernel(
    const void* __restrict__ idxraw, int* __restrict__ cursor,
    int* __restrict__ eid)
{
    const bool i64 = idx_is_i64(idxraw);
    const int e = blockIdx.x * 256 + threadIdx.x;
    const int pos = atomicAdd(&cursor[load_idx(idxraw, i64, e)], 1);
    eid[pos] = e;
}

// ---------------------------------------------------------------------------
// Kernel 4 (fused): gather-transform into LDS, then MLP.
//   gather: wave wv owns rows wv*8..wv*8+7 of the 32-row tile; per node the
//   wave walks its CSR list 4 edges at a time (4 independent accumulator
//   pairs -> ~2.3 KB of loads in flight per wave). Lane owns hidden dims
//   {2*lane, 2*lane+1}; its two W_pair columns sit in 32 VGPRs. offs[n+1]
//   is carried to the next iteration (consecutive nodes share boundaries).
//   MLP: 8x4 micro-tile per thread; h2 never materialized (W3 folded into
//   epilogue + 64-lane shuffle reduce). LDS 48KB -> 3 blocks/CU; peak VGPR
//   ~135 < 170 cap from (256,3).
// ---------------------------------------------------------------------------
__global__ __launch_bounds__(256, 3) void fused_kernel(
    const float* __restrict__ x, const float* __restrict__ pb,
    const int* __restrict__ eid, const int* __restrict__ offs,
    const float* __restrict__ Wp, const float* __restrict__ W1,
    const float* __restrict__ W2, const float* __restrict__ b2,
    const float* __restrict__ W3, float* __restrict__ out)
{
    __shared__ float sN[32][H];    // 16 KB
    __shared__ float sH[32][OE];   // 32 KB

    const int t    = threadIdx.x;
    const int lane = t & 63;
    const int wv   = t >> 6;
    const int row0 = blockIdx.x * 32;
    const int n0   = row0 + wv * 8;

    // My two W_pair columns: Wp[k][2*lane], Wp[k][2*lane+1].
    float2 wcol[P];
#pragma unroll
    for (int k = 0; k < P; ++k)
        wcol[k] = *reinterpret_cast<const float2*>(&Wp[k * H + 2 * lane]);

    const float4* pb4 = reinterpret_cast<const float4*>(pb);
    const float2* x2  = reinterpret_cast<const float2*>(x);

    // ---- gather phase: 8 consecutive nodes per wave ----
    int nxt = (n0 < NN) ? offs[n0] : 0;     // offs[n] for the next iteration
    for (int j = 0; j < 8; ++j) {
        const int n = n0 + j;
        float s0 = 0.f, s1 = 0.f;
        if (n < NN) {
            const int lo = nxt;
            const int hi = offs[n + 1];
            nxt = hi;
            float acc0[4] = {0.f, 0.f, 0.f, 0.f};
            float acc1[4] = {0.f, 0.f, 0.f, 0.f};
            int p = lo;
            for (; p + 4 <= hi; p += 4) {
                int e4[4];
#pragma unroll
                for (int q = 0; q < 4; ++q) e4[q] = eid[p + q];
                float4 B[4][4];
                float2 X[4];
#pragma unroll
                for (int q = 0; q < 4; ++q) {
                    const long b = (long)e4[q] * 4;
                    B[q][0] = pb4[b + 0];
                    B[q][1] = pb4[b + 1];
                    B[q][2] = pb4[b + 2];
                    B[q][3] = pb4[b + 3];
                    X[q]    = x2[(long)e4[q] * 64 + lane];
                }
#pragma unroll
                for (int q = 0; q < 4; ++q) {
                    float p0, p1;
                    p0  = B[q][0].x * wcol[0].x;   p1  = B[q][0].x * wcol[0].y;
                    p0 += B[q][0].y * wcol[1].x;   p1 += B[q][0].y * wcol[1].y;
                    p0 += B[q][0].z * wcol[2].x;   p1 += B[q][0].z * wcol[2].y;
                    p0 += B[q][0].w * wcol[3].x;   p1 += B[q][0].w * wcol[3].y;
                    p0 += B[q][1].x * wcol[4].x;   p1 += B[q][1].x * wcol[4].y;
                    p0 += B[q][1].y * wcol[5].x;   p1 += B[q][1].y * wcol[5].y;
                    p0 += B[q][1].z * wcol[6].x;   p1 += B[q][1].z * wcol[6].y;
                    p0 += B[q][1].w * wcol[7].x;   p1 += B[q][1].w * wcol[7].y;
                    p0 += B[q][2].x * wcol[8].x;   p1 += B[q][2].x * wcol[8].y;
                    p0 += B[q][2].y * wcol[9].x;   p1 += B[q][2].y * wcol[9].y;
                    p0 += B[q][2].z * wcol[10].x;  p1 += B[q][2].z * wcol[10].y;
                    p0 += B[q][2].w * wcol[11].x;  p1 += B[q][2].w * wcol[11].y;
                    p0 += B[q][3].x * wcol[12].x;  p1 += B[q][3].x * wcol[12].y;
                    p0 += B[q][3].y * wcol[13].x;  p1 += B[q][3].y * wcol[13].y;
                    p0 += B[q][3].z * wcol[14].x;  p1 += B[q][3].z * wcol[14].y;
                    p0 += B[q][3].w * wcol[15].x;  p1 += B[q][3].w * wcol[15].y;
                    acc0[q] += p0 * X[q].x;
                    acc1[q] += p1 * X[q].y;
                }
            }
            for (; p < hi; ++p) {                 // tail 0..3 edges
                const int e = eid[p];
                const long b = (long)e * 4;
                const float4 B0 = pb4[b + 0], B1 = pb4[b + 1];
                const float4 B2 = pb4[b + 2], B3 = pb4[b + 3];
                const float2 X0 = x2[(long)e * 64 + lane];
                float p0, p1;
                p0  = B0.x * wcol[0].x;   p1  = B0.x * wcol[0].y;
                p0 += B0.y * wcol[1].x;   p1 += B0.y * wcol[1].y;
                p0 += B0.z * wcol[2].x;   p1 += B0.z * wcol[2].y;
                p0 += B0.w * wcol[3].x;   p1 += B0.w * wcol[3].y;
                p0 += B1.x * wcol[4].x;   p1 += B1.x * wcol[4].y;
                p0 += B1.y * wcol[5].x;   p1 += B1.y * wcol[5].y;
                p0 += B1.z * wcol[6].x;   p1 += B1.z * wcol[6].y;
                p0 += B1.w * wcol[7].x;   p1 += B1.w * wcol[7].y;
                p0 += B2.x * wcol[8].x;   p1 += B2.x * wcol[8].y;
                p0 += B2.y * wcol[9].x;   p1 += B2.y * wcol[9].y;
                p0 += B2.z * wcol[10].x;  p1 += B2.z * wcol[10].y;
                p0 += B2.w * wcol[11].x;  p1 += B2.w * wcol[11].y;
                p0 += B3.x * wcol[12].x;  p1 += B3.x * wcol[12].y;
                p0 += B3.y * wcol[13].x;  p1 += B3.y * wcol[13].y;
                p0 += B3.z * wcol[14].x;  p1 += B3.z * wcol[14].y;
                p0 += B3.w * wcol[15].x;  p1 += B3.w * wcol[15].y;
                acc0[0] += p0 * X0.x;
                acc1[0] += p1 * X0.y;
            }
            s0 = (acc0[0] + acc0[1]) + (acc0[2] + acc0[3]);
            s1 = (acc1[0] + acc1[1]) + (acc1[2] + acc1[3]);
        }
        *reinterpret_cast<float2*>(&sN[wv * 8 + j][2 * lane]) =
            make_float2(s0, s1);
    }
    __syncthreads();

    // ---- MLP phase ----
    const int c0 = lane * 4;
    const int r0 = wv * 8;

    // layer 1: h1 = silu(node @ W1), K = 128
    float acc[8][4];
#pragma unroll
    for (int r = 0; r < 8; ++r)
#pragma unroll
        for (int c = 0; c < 4; ++c) acc[r][c] = 0.f;

    for (int k = 0; k < H; k += 4) {
        float a[8][4];
#pragma unroll
        for (int r = 0; r < 8; ++r) {
            const float4 v = *reinterpret_cast<const float4*>(&sN[r0 + r][k]); // wave-uniform broadcast
            a[r][0] = v.x; a[r][1] = v.y; a[r][2] = v.z; a[r][3] = v.w;
        }
#pragma unroll
        for (int kk = 0; kk < 4; ++kk) {
            const float4 w = *reinterpret_cast<const float4*>(&W1[(k + kk) * OE + c0]); // coalesced, L2-hit
#pragma unroll
            for (int r = 0; r < 8; ++r) {
                const float av = a[r][kk];
                acc[r][0] += av * w.x; acc[r][1] += av * w.y;
                acc[r][2] += av * w.z; acc[r][3] += av * w.w;
            }
        }
    }
#pragma unroll
    for (int r = 0; r < 8; ++r)
#pragma unroll
        for (int c = 0; c < 4; ++c)
            sH[r0 + r][c0 + c] = silu(acc[r][c]);
    __syncthreads();

    // layer 2: h2 = silu(h1 @ W2 + b2), K = 256, W3 fused
    float acc2[8][4];
#pragma unroll
    for (int r = 0; r < 8; ++r)
#pragma unroll
        for (int c = 0; c < 4; ++c) acc2[r][c] = 0.f;

    for (int k = 0; k < OE; k += 4) {
        float a[8][4];
#pragma unroll
        for (int r = 0; r < 8; ++r) {
            const float4 v = *reinterpret_cast<const float4*>(&sH[r0 + r][k]);
            a[r][0] = v.x; a[r][1] = v.y; a[r][2] = v.z; a[r][3] = v.w;
        }
#pragma unroll
        for (int kk = 0; kk < 4; ++kk) {
            const float4 w = *reinterpret_cast<const float4*>(&W2[(k + kk) * OE + c0]);
#pragma unroll
            for (int r = 0; r < 8; ++r) {
                const float av = a[r][kk];
                acc2[r][0] += av * w.x; acc2[r][1] += av * w.y;
                acc2[r][2] += av * w.z; acc2[r][3] += av * w.w;
            }
        }
    }

    const float4 bb = *reinterpret_cast<const float4*>(&b2[c0]);
    const float4 w3 = *reinterpret_cast<const float4*>(&W3[c0]);
    float part[8];
#pragma unroll
    for (int r = 0; r < 8; ++r) {
        part[r] = silu(acc2[r][0] + bb.x) * w3.x
                + silu(acc2[r][1] + bb.y) * w3.y
                + silu(acc2[r][2] + bb.z) * w3.z
                + silu(acc2[r][3] + bb.w) * w3.w;
    }
#pragma unroll
    for (int r = 0; r < 8; ++r) {
        float p = part[r];
#pragma unroll
        for (int off = 32; off > 0; off >>= 1)
            p += __shfl_down(p, off, 64);
        part[r] = p;
    }
    if (lane == 0) {
#pragma unroll
        for (int r = 0; r < 8; ++r) {
            const int row = row0 + r0 + r;
            if (row < NN) out[row] = part[r];
        }
    }
}

extern "C" void kernel_launch(void* const* d_in, const int* in_sizes, int n_in,
                              void* d_out, int out_size, void* d_ws, size_t ws_size,
                              hipStream_t stream) {
    const float* x   = (const float*)d_in[0];
    const float* pb  = (const float*)d_in[1];
    const void*  idx = d_in[2];          // int32 or int64 — detected per wave
    // d_in[3] = num_nodes scalar (compile-time constant NN)
    const float* Wp  = (const float*)d_in[4];
    const float* W1  = (const float*)d_in[5];
    const float* W2  = (const float*)d_in[6];
    const float* b2  = (const float*)d_in[7];
    const float* W3  = (const float*)d_in[8];
    float* out = (float*)d_out;

    char* w = (char*)d_ws;
    int* cnt    = (int*)(w + OFF_CNT);     // becomes offs after scan
    int* cursor = (int*)(w + OFF_CURSOR);
    int* eid    = (int*)(w + OFF_EID);

    hipMemsetAsync(cnt, 0, (NN + 1) * sizeof(int), stream);
    hist_kernel<<<E / 256, 256, 0, stream>>>(idx, cnt);
    scan_kernel<<<1, 1024, 0, stream>>>(cnt, cursor);
    fill_kernel<<<E / 256, 256, 0, stream>>>(idx, cursor, eid);
    fused_kernel<<<(NN + 31) / 32, 256, 0, stream>>>(
        x, pb, eid, cnt, Wp, W1, W2, b2, W3, out);
}

// Round 6
// 770.430 us; speedup vs baseline: 1.1303x; 1.1303x over previous
//
#include <hip/hip_runtime.h>

// Problem constants (from reference).
constexpr int E  = 640000;   // edges (= 2500 * 256 exactly)
constexpr int H  = 128;      // hidden
constexpr int P  = 16;       // pair dim
constexpr int NN = 50000;    // nodes (NN % 4 == 0)
constexpr int OE = 256;      // out emb
constexpr int CAPMAX = 64;   // eid slots per node; P(Poisson(12.8) > 64) ~ 1e-24
constexpr int OVMAX  = 65536;

// ws layout (bytes):
//   node : NN*H*4 = 25,600,000
//   cnt  : NN*4 (padded)      — per-node degree counters
//   ovc  : overflow counter
//   ovf  : OVMAX*4            — overflow edge list
//   eid  : NN*cap*4           — slot table (cap chosen from ws_size, <= 64)
constexpr size_t OFF_NODE = 0;
constexpr size_t OFF_CNT  = 25600000;
constexpr size_t OFF_OVC  = OFF_CNT + 200192;
constexpr size_t OFF_OVF  = OFF_OVC + 256;
constexpr size_t OFF_EID  = OFF_OVF + 262144;   // = 26,062,592; +NN*64*4 -> 38.9 MB

__device__ __forceinline__ float silu(float v) {
    return v / (1.f + __expf(-v));
}

// Per-wave idx dtype detection (reads words 1..255 only — safe both layouts).
// int32 random: odd words ~never all zero; LE int64 (<2^31): odd words all 0.
__device__ __forceinline__ bool idx_is_i64(const void* idxraw) {
    const unsigned* u = (const unsigned*)idxraw;
    const int lane = threadIdx.x & 63;
    const unsigned v = u[2 * lane + 1] | u[2 * lane + 129];
    return !__any(v != 0);
}

__device__ __forceinline__ int load_idx(const void* idxraw, bool i64, int e) {
    return i64 ? (int)((const long long*)idxraw)[e]
               : ((const int*)idxraw)[e];
}

// ---------------------------------------------------------------------------
// Kernel 1: slot_fill — one pass, one atomic per edge. Replaces hist+scan+fill.
// ---------------------------------------------------------------------------
__global__ __launch_bounds__(256) void slot_fill_kernel(
    const void* __restrict__ idxraw, const int cap,
    int* __restrict__ cnt, int* __restrict__ ovc,
    int* __restrict__ ovf, int* __restrict__ eid)
{
    const bool i64 = idx_is_i64(idxraw);
    const int e = blockIdx.x * 256 + threadIdx.x;
    const int n = load_idx(idxraw, i64, e);
    const int pos = atomicAdd(&cnt[n], 1);
    if (pos < cap) {
        eid[(long)n * cap + pos] = e;
    } else {
        const int o = atomicAdd(ovc, 1);
        if (o < OVMAX) ovf[o] = e;
    }
}

// ---------------------------------------------------------------------------
// Kernel 2: gather — one node per wave, no LDS, 16 waves/CU.
// Lane owns dims {2*lane, 2*lane+1}; W_pair columns in 32 VGPRs. Two
// independent edge chains per iteration (~18 KB/CU of loads in flight).
// Writes the full node row (deg-0 rows get zeros) — no node memset needed.
// ---------------------------------------------------------------------------
__device__ __forceinline__ void edge_contrib(
    const float4* __restrict__ pb4, const float2* __restrict__ x2,
    const float2 (&wcol)[P], int e, int lane, float& o0, float& o1)
{
    const long b = (long)e * 4;
    const float4 B0 = pb4[b + 0], B1 = pb4[b + 1];
    const float4 B2 = pb4[b + 2], B3 = pb4[b + 3];
    const float2 X  = x2[(long)e * 64 + lane];
    float p0, p1;
    p0  = B0.x * wcol[0].x;   p1  = B0.x * wcol[0].y;
    p0 += B0.y * wcol[1].x;   p1 += B0.y * wcol[1].y;
    p0 += B0.z * wcol[2].x;   p1 += B0.z * wcol[2].y;
    p0 += B0.w * wcol[3].x;   p1 += B0.w * wcol[3].y;
    p0 += B1.x * wcol[4].x;   p1 += B1.x * wcol[4].y;
    p0 += B1.y * wcol[5].x;   p1 += B1.y * wcol[5].y;
    p0 += B1.z * wcol[6].x;   p1 += B1.z * wcol[6].y;
    p0 += B1.w * wcol[7].x;   p1 += B1.w * wcol[7].y;
    p0 += B2.x * wcol[8].x;   p1 += B2.x * wcol[8].y;
    p0 += B2.y * wcol[9].x;   p1 += B2.y * wcol[9].y;
    p0 += B2.z * wcol[10].x;  p1 += B2.z * wcol[10].y;
    p0 += B2.w * wcol[11].x;  p1 += B2.w * wcol[11].y;
    p0 += B3.x * wcol[12].x;  p1 += B3.x * wcol[12].y;
    p0 += B3.y * wcol[13].x;  p1 += B3.y * wcol[13].y;
    p0 += B3.z * wcol[14].x;  p1 += B3.z * wcol[14].y;
    p0 += B3.w * wcol[15].x;  p1 += B3.w * wcol[15].y;
    o0 = p0 * X.x;
    o1 = p1 * X.y;
}

__global__ __launch_bounds__(256, 4) void gather_kernel(
    const float* __restrict__ x, const float* __restrict__ pb,
    const int* __restrict__ cnt, const int* __restrict__ eid, const int cap,
    const float* __restrict__ Wp, float* __restrict__ node)
{
    const int lane = threadIdx.x & 63;
    const int n    = blockIdx.x * 4 + (threadIdx.x >> 6);   // NN/4 blocks exactly

    float2 wcol[P];
#pragma unroll
    for (int k = 0; k < P; ++k)
        wcol[k] = *reinterpret_cast<const float2*>(&Wp[k * H + 2 * lane]);

    const float4* pb4 = reinterpret_cast<const float4*>(pb);
    const float2* x2  = reinterpret_cast<const float2*>(x);
    const int* slots  = eid + (long)n * cap;
    const int deg = min(cnt[n], cap);

    float a0 = 0.f, a1 = 0.f, b0 = 0.f, b1 = 0.f;
    int p = 0;
    for (; p + 2 <= deg; p += 2) {
        const int e0 = slots[p], e1 = slots[p + 1];
        float u0, u1, v0, v1;
        edge_contrib(pb4, x2, wcol, e0, lane, u0, u1);
        edge_contrib(pb4, x2, wcol, e1, lane, v0, v1);
        a0 += u0; a1 += u1; b0 += v0; b1 += v1;
    }
    if (p < deg) {
        float u0, u1;
        edge_contrib(pb4, x2, wcol, slots[p], lane, u0, u1);
        a0 += u0; a1 += u1;
    }
    *reinterpret_cast<float2*>(&node[(long)n * H + 2 * lane]) =
        make_float2(a0 + b0, a1 + b1);
}

// ---------------------------------------------------------------------------
// Kernel 3: overflow cleanup — atomically adds overflow edges into node rows.
// Normally processes 0 edges (cap=64 never overflows); correctness net only.
// ---------------------------------------------------------------------------
__global__ __launch_bounds__(256) void ovf_apply_kernel(
    const float* __restrict__ x, const float* __restrict__ pb,
    const void* __restrict__ idxraw, const int* __restrict__ ovc,
    const int* __restrict__ ovf, const float* __restrict__ Wp,
    float* __restrict__ node)
{
    const int m = min(*ovc, OVMAX);
    if (m == 0) return;
    const bool i64 = idx_is_i64(idxraw);
    const int lane = threadIdx.x & 63;
    const int wv   = threadIdx.x >> 6;

    float2 wcol[P];
#pragma unroll
    for (int k = 0; k < P; ++k)
        wcol[k] = *reinterpret_cast<const float2*>(&Wp[k * H + 2 * lane]);
    const float4* pb4 = reinterpret_cast<const float4*>(pb);
    const float2* x2  = reinterpret_cast<const float2*>(x);

    for (int k = wv; k < m; k += 4) {
        const int e = ovf[k];
        const int n = load_idx(idxraw, i64, e);
        float u0, u1;
        edge_contrib(pb4, x2, wcol, e, lane, u0, u1);
        atomicAdd(&node[(long)n * H + 2 * lane], u0);
        atomicAdd(&node[(long)n * H + 2 * lane + 1], u1);
    }
}

// ---------------------------------------------------------------------------
// Kernel 4: fused MLP  out = silu(silu(node@W1) @ W2 + b2) @ W3
// 32 rows/block, 256 threads, 8x4 micro-tile/thread; W3 folded into epilogue
// + 64-lane shuffle reduce. LDS 48KB -> 3 blocks/CU.
// ---------------------------------------------------------------------------
__global__ __launch_bounds__(256) void mlp_kernel(
    const float* __restrict__ node, const float* __restrict__ W1,
    const float* __restrict__ W2, const float* __restrict__ b2,
    const float* __restrict__ W3, float* __restrict__ out)
{
    __shared__ float sN[32][H];    // 16 KB
    __shared__ float sH[32][OE];   // 32 KB

    const int t    = threadIdx.x;
    const int row0 = blockIdx.x * 32;

#pragma unroll
    for (int i = 0; i < 4; ++i) {
        const int lin = t + i * 256;
        const int r   = lin >> 5;
        const int c   = (lin & 31) * 4;
        float4 v = make_float4(0.f, 0.f, 0.f, 0.f);
        if (row0 + r < NN)
            v = *reinterpret_cast<const float4*>(&node[(long)(row0 + r) * H + c]);
        *reinterpret_cast<float4*>(&sN[r][c]) = v;
    }
    __syncthreads();

    const int tc = t & 63;
    const int tr = t >> 6;
    const int c0 = tc * 4;
    const int r0 = tr * 8;

    // layer 1: h1 = silu(node @ W1), K = 128
    float acc[8][4];
#pragma unroll
    for (int r = 0; r < 8; ++r)
#pragma unroll
        for (int c = 0; c < 4; ++c) acc[r][c] = 0.f;

    for (int k = 0; k < H; k += 4) {
        float a[8][4];
#pragma unroll
        for (int r = 0; r < 8; ++r) {
            const float4 v = *reinterpret_cast<const float4*>(&sN[r0 + r][k]); // wave-uniform broadcast
            a[r][0] = v.x; a[r][1] = v.y; a[r][2] = v.z; a[r][3] = v.w;
        }
#pragma unroll
        for (int kk = 0; kk < 4; ++kk) {
            const float4 w = *reinterpret_cast<const float4*>(&W1[(k + kk) * OE + c0]); // coalesced, L2-hit
#pragma unroll
            for (int r = 0; r < 8; ++r) {
                const float av = a[r][kk];
                acc[r][0] += av * w.x; acc[r][1] += av * w.y;
                acc[r][2] += av * w.z; acc[r][3] += av * w.w;
            }
        }
    }
#pragma unroll
    for (int r = 0; r < 8; ++r)
#pragma unroll
        for (int c = 0; c < 4; ++c)
            sH[r0 + r][c0 + c] = silu(acc[r][c]);
    __syncthreads();

    // layer 2: h2 = silu(h1 @ W2 + b2), K = 256, W3 fused
    float acc2[8][4];
#pragma unroll
    for (int r = 0; r < 8; ++r)
#pragma unroll
        for (int c = 0; c < 4; ++c) acc2[r][c] = 0.f;

    for (int k = 0; k < OE; k += 4) {
        float a[8][4];
#pragma unroll
        for (int r = 0; r < 8; ++r) {
            const float4 v = *reinterpret_cast<const float4*>(&sH[r0 + r][k]);
            a[r][0] = v.x; a[r][1] = v.y; a[r][2] = v.z; a[r][3] = v.w;
        }
#pragma unroll
        for (int kk = 0; kk < 4; ++kk) {
            const float4 w = *reinterpret_cast<const float4*>(&W2[(k + kk) * OE + c0]);
#pragma unroll
            for (int r = 0; r < 8; ++r) {
                const float av = a[r][kk];
                acc2[r][0] += av * w.x; acc2[r][1] += av * w.y;
                acc2[r][2] += av * w.z; acc2[r][3] += av * w.w;
            }
        }
    }

    const float4 bb = *reinterpret_cast<const float4*>(&b2[c0]);
    const float4 w3 = *reinterpret_cast<const float4*>(&W3[c0]);
    float part[8];
#pragma unroll
    for (int r = 0; r < 8; ++r) {
        part[r] = silu(acc2[r][0] + bb.x) * w3.x
                + silu(acc2[r][1] + bb.y) * w3.y
                + silu(acc2[r][2] + bb.z) * w3.z
                + silu(acc2[r][3] + bb.w) * w3.w;
    }
#pragma unroll
    for (int r = 0; r < 8; ++r) {
        float p = part[r];
#pragma unroll
        for (int off = 32; off > 0; off >>= 1)
            p += __shfl_down(p, off, 64);
        part[r] = p;
    }
    if (tc == 0) {
#pragma unroll
        for (int r = 0; r < 8; ++r) {
            const int row = row0 + r0 + r;
            if (row < NN) out[row] = part[r];
        }
    }
}

extern "C" void kernel_launch(void* const* d_in, const int* in_sizes, int n_in,
                              void* d_out, int out_size, void* d_ws, size_t ws_size,
                              hipStream_t stream) {
    const float* x   = (const float*)d_in[0];
    const float* pb  = (const float*)d_in[1];
    const void*  idx = d_in[2];          // int32 or int64 — detected per wave
    // d_in[3] = num_nodes scalar (compile-time constant NN)
    const float* Wp  = (const float*)d_in[4];
    const float* W1  = (const float*)d_in[5];
    const float* W2  = (const float*)d_in[6];
    const float* b2  = (const float*)d_in[7];
    const float* W3  = (const float*)d_in[8];
    float* out = (float*)d_out;

    char* w = (char*)d_ws;
    float* node = (float*)(w + OFF_NODE);
    int*   cnt  = (int*)(w + OFF_CNT);
    int*   ovc  = (int*)(w + OFF_OVC);
    int*   ovf  = (int*)(w + OFF_OVF);
    int*   eid  = (int*)(w + OFF_EID);

    // Slot capacity from available workspace (target 64).
    int cap = CAPMAX;
    if (ws_size > OFF_EID) {
        const size_t fit = (ws_size - OFF_EID) / ((size_t)NN * sizeof(int));
        if (fit < (size_t)cap) cap = (int)fit;
    }
    if (cap < 1) cap = 1;

    hipMemsetAsync(w + OFF_CNT, 0, 200192 + 256, stream);  // cnt + ovc
    slot_fill_kernel<<<E / 256, 256, 0, stream>>>(idx, cap, cnt, ovc, ovf, eid);
    gather_kernel<<<NN / 4, 256, 0, stream>>>(x, pb, cnt, eid, cap, Wp, node);
    ovf_apply_kernel<<<1, 256, 0, stream>>>(x, pb, idx, ovc, ovf, Wp, node);
    mlp_kernel<<<(NN + 31) / 32, 256, 0, stream>>>(node, W1, W2, b2, W3, out);
}

// Round 7
// 682.092 us; speedup vs baseline: 1.2766x; 1.1295x over previous
//
#include <hip/hip_runtime.h>

// Problem constants (from reference).
constexpr int E  = 640000;   // edges (= 2500 * 256 exactly)
constexpr int H  = 128;      // hidden
constexpr int P  = 16;       // pair dim
constexpr int NN = 50000;    // nodes (NN % 4 == 0)
constexpr int OE = 256;      // out emb
constexpr int CAPMAX = 64;   // eid slots per node; P(Poisson(12.8) > 64) ~ 1e-24
constexpr int OVMAX  = 65536;
constexpr int BATCH  = 8;    // edges staged per global_load_lds batch

// ws layout (bytes):
//   node : NN*H*4 = 25,600,000
//   cnt  : NN*4 (padded)  — per-node degree counters
//   ovc  : overflow counter
//   ovf  : OVMAX*4        — overflow edge list
//   eid  : NN*cap*4       — slot table (cap from ws_size, <= 64)
constexpr size_t OFF_NODE = 0;
constexpr size_t OFF_CNT  = 25600000;
constexpr size_t OFF_OVC  = OFF_CNT + 200192;
constexpr size_t OFF_OVF  = OFF_OVC + 256;
constexpr size_t OFF_EID  = OFF_OVF + 262144;   // +NN*64*4 -> 38.9 MB

__device__ __forceinline__ float silu(float v) {
    return v / (1.f + __expf(-v));
}

// Async global->LDS DMA, 16B per lane. LDS dest = (wave-uniform base) + lane*16.
__device__ __forceinline__ void ldsdma16(void* lds, const void* g) {
    __builtin_amdgcn_global_load_lds(
        (const __attribute__((address_space(1))) void*)g,
        (__attribute__((address_space(3))) void*)lds, 16, 0, 0);
}

// Per-wave idx dtype detection (reads words 1..255 only — safe both layouts).
__device__ __forceinline__ bool idx_is_i64(const void* idxraw) {
    const unsigned* u = (const unsigned*)idxraw;
    const int lane = threadIdx.x & 63;
    const unsigned v = u[2 * lane + 1] | u[2 * lane + 129];
    return !__any(v != 0);
}

__device__ __forceinline__ int load_idx(const void* idxraw, bool i64, int e) {
    return i64 ? (int)((const long long*)idxraw)[e]
               : ((const int*)idxraw)[e];
}

// ---------------------------------------------------------------------------
// Kernel 1: slot_fill — one atomic per edge (measured in isolation this round).
// ---------------------------------------------------------------------------
__global__ __launch_bounds__(256) void slot_fill_kernel(
    const void* __restrict__ idxraw, const int cap,
    int* __restrict__ cnt, int* __restrict__ ovc,
    int* __restrict__ ovf, int* __restrict__ eid)
{
    const bool i64 = idx_is_i64(idxraw);
    const int e = blockIdx.x * 256 + threadIdx.x;
    const int n = load_idx(idxraw, i64, e);
    const int pos = atomicAdd(&cnt[n], 1);
    if (pos < cap) {
        eid[(long)n * cap + pos] = e;
    } else {
        const int o = atomicAdd(ovc, 1);
        if (o < OVMAX) ovf[o] = e;
    }
}

// ---------------------------------------------------------------------------
// Kernel 2: gather — wave per node; edges staged 8-at-a-time into LDS via
// global_load_lds (fire-and-forget DMA: no VGPR pressure, all 5 instructions
// in flight together -> breaks the serial-load chain that made R6 latency-
// bound at VGPR_Count=40). Lane owns dims {2*lane, 2*lane+1}; W_pair columns
// in 32 VGPRs. LDS 20KB/block; 6 blocks/CU -> 24 waves/CU.
// ---------------------------------------------------------------------------
__global__ __launch_bounds__(256, 6) void gather_kernel(
    const float* __restrict__ x, const float* __restrict__ pb,
    const int* __restrict__ cnt, const int* __restrict__ eid, const int cap,
    const float* __restrict__ Wp, float* __restrict__ node)
{
    __shared__ float x_lds[4][BATCH][H];     // 16 KB: staged x rows
    __shared__ float pb_lds[4][2 * BATCH][P]; // 4 KB: staged pb rows (upper half = junk)

    const int lane = threadIdx.x & 63;
    const int wv   = threadIdx.x >> 6;
    const int n    = blockIdx.x * 4 + wv;    // NN/4 blocks exactly

    float2 wcol[P];
#pragma unroll
    for (int k = 0; k < P; ++k)
        wcol[k] = *reinterpret_cast<const float2*>(&Wp[k * H + 2 * lane]);

    const char* xb  = (const char*)x;
    const char* pbb = (const char*)pb;
    const int* slots = eid + (long)n * cap;
    const int deg = min(cnt[n], cap);

    float a0 = 0.f, a1 = 0.f;
    for (int base = 0; base < deg; base += BATCH) {
        const int m = min(BATCH, deg - base);
        // Lane l holds slot base+l (dummy = first slot for tail lanes).
        const int ev = (lane < m) ? slots[base + lane] : slots[base];

        // Stage x rows: instruction j covers edges 2j (lanes 0-31) and 2j+1.
#pragma unroll
        for (int j = 0; j < BATCH / 2; ++j) {
            if (2 * j < m) {
                const int elo = __shfl(ev, 2 * j);
                const int ehi = __shfl(ev, 2 * j + 1);
                const char* g = (lane < 32)
                    ? xb + (size_t)elo * 512 + (size_t)lane * 16
                    : xb + (size_t)ehi * 512 + (size_t)(lane - 32) * 16;
                ldsdma16(&x_lds[wv][2 * j][0], g);
            }
        }
        // Stage pb rows: lane l covers edge (l>>2)&7, bytes (l&3)*16.
        {
            const int eq = __shfl(ev, (lane >> 2) & 7);
            const char* g = pbb + (size_t)eq * 64 + (size_t)(lane & 3) * 16;
            ldsdma16(&pb_lds[wv][0][0], g);
        }
        asm volatile("s_waitcnt vmcnt(0)" ::: "memory");

        for (int i = 0; i < m; ++i) {
            const float2 xv = *reinterpret_cast<const float2*>(&x_lds[wv][i][2 * lane]);
            const float4 B0 = *reinterpret_cast<const float4*>(&pb_lds[wv][i][0]);
            const float4 B1 = *reinterpret_cast<const float4*>(&pb_lds[wv][i][4]);
            const float4 B2 = *reinterpret_cast<const float4*>(&pb_lds[wv][i][8]);
            const float4 B3 = *reinterpret_cast<const float4*>(&pb_lds[wv][i][12]);
            float p0, p1;
            p0  = B0.x * wcol[0].x;   p1  = B0.x * wcol[0].y;
            p0 += B0.y * wcol[1].x;   p1 += B0.y * wcol[1].y;
            p0 += B0.z * wcol[2].x;   p1 += B0.z * wcol[2].y;
            p0 += B0.w * wcol[3].x;   p1 += B0.w * wcol[3].y;
            p0 += B1.x * wcol[4].x;   p1 += B1.x * wcol[4].y;
            p0 += B1.y * wcol[5].x;   p1 += B1.y * wcol[5].y;
            p0 += B1.z * wcol[6].x;   p1 += B1.z * wcol[6].y;
            p0 += B1.w * wcol[7].x;   p1 += B1.w * wcol[7].y;
            p0 += B2.x * wcol[8].x;   p1 += B2.x * wcol[8].y;
            p0 += B2.y * wcol[9].x;   p1 += B2.y * wcol[9].y;
            p0 += B2.z * wcol[10].x;  p1 += B2.z * wcol[10].y;
            p0 += B2.w * wcol[11].x;  p1 += B2.w * wcol[11].y;
            p0 += B3.x * wcol[12].x;  p1 += B3.x * wcol[12].y;
            p0 += B3.y * wcol[13].x;  p1 += B3.y * wcol[13].y;
            p0 += B3.z * wcol[14].x;  p1 += B3.z * wcol[14].y;
            p0 += B3.w * wcol[15].x;  p1 += B3.w * wcol[15].y;
            a0 += p0 * xv.x;
            a1 += p1 * xv.y;
        }
    }
    *reinterpret_cast<float2*>(&node[(long)n * H + 2 * lane]) =
        make_float2(a0, a1);
}

// ---------------------------------------------------------------------------
// Kernel 3: overflow cleanup (normally 0 edges; correctness net only).
// ---------------------------------------------------------------------------
__global__ __launch_bounds__(256) void ovf_apply_kernel(
    const float* __restrict__ x, const float* __restrict__ pb,
    const void* __restrict__ idxraw, const int* __restrict__ ovc,
    const int* __restrict__ ovf, const float* __restrict__ Wp,
    float* __restrict__ node)
{
    const int m = min(*ovc, OVMAX);
    if (m == 0) return;
    const bool i64 = idx_is_i64(idxraw);
    const int lane = threadIdx.x & 63;
    const int wv   = threadIdx.x >> 6;

    float2 wcol[P];
#pragma unroll
    for (int k = 0; k < P; ++k)
        wcol[k] = *reinterpret_cast<const float2*>(&Wp[k * H + 2 * lane]);
    const float4* pb4 = reinterpret_cast<const float4*>(pb);
    const float2* x2  = reinterpret_cast<const float2*>(x);

    for (int kk = wv; kk < m; kk += 4) {
        const int e = ovf[kk];
        const int n = load_idx(idxraw, i64, e);
        const long b = (long)e * 4;
        const float4 B0 = pb4[b + 0], B1 = pb4[b + 1];
        const float4 B2 = pb4[b + 2], B3 = pb4[b + 3];
        const float2 X  = x2[(long)e * 64 + lane];
        float p0, p1;
        p0  = B0.x * wcol[0].x;   p1  = B0.x * wcol[0].y;
        p0 += B0.y * wcol[1].x;   p1 += B0.y * wcol[1].y;
        p0 += B0.z * wcol[2].x;   p1 += B0.z * wcol[2].y;
        p0 += B0.w * wcol[3].x;   p1 += B0.w * wcol[3].y;
        p0 += B1.x * wcol[4].x;   p1 += B1.x * wcol[4].y;
        p0 += B1.y * wcol[5].x;   p1 += B1.y * wcol[5].y;
        p0 += B1.z * wcol[6].x;   p1 += B1.z * wcol[6].y;
        p0 += B1.w * wcol[7].x;   p1 += B1.w * wcol[7].y;
        p0 += B2.x * wcol[8].x;   p1 += B2.x * wcol[8].y;
        p0 += B2.y * wcol[9].x;   p1 += B2.y * wcol[9].y;
        p0 += B2.z * wcol[10].x;  p1 += B2.z * wcol[10].y;
        p0 += B2.w * wcol[11].x;  p1 += B2.w * wcol[11].y;
        p0 += B3.x * wcol[12].x;  p1 += B3.x * wcol[12].y;
        p0 += B3.y * wcol[13].x;  p1 += B3.y * wcol[13].y;
        p0 += B3.z * wcol[14].x;  p1 += B3.z * wcol[14].y;
        p0 += B3.w * wcol[15].x;  p1 += B3.w * wcol[15].y;
        atomicAdd(&node[(long)n * H + 2 * lane], p0 * X.x);
        atomicAdd(&node[(long)n * H + 2 * lane + 1], p1 * X.y);
    }
}

// ---------------------------------------------------------------------------
// Kernel 4: fused MLP  out = silu(silu(node@W1) @ W2 + b2) @ W3
// LDS union: sN(16KB) and sH(32KB) share one 32KB buffer (layer-1 result
// lives in registers across the swap) -> 5 blocks/CU, 20 waves/CU.
// ---------------------------------------------------------------------------
__global__ __launch_bounds__(256, 5) void mlp_kernel(
    const float* __restrict__ node, const float* __restrict__ W1,
    const float* __restrict__ W2, const float* __restrict__ b2,
    const float* __restrict__ W3, float* __restrict__ out)
{
    __shared__ float sB[32 * OE];   // 32 KB, aliased: sN=[32][128] then sH=[32][256]

    const int t    = threadIdx.x;
    const int row0 = blockIdx.x * 32;

#pragma unroll
    for (int i = 0; i < 4; ++i) {
        const int lin = t + i * 256;
        const int r   = lin >> 5;
        const int c   = (lin & 31) * 4;
        float4 v = make_float4(0.f, 0.f, 0.f, 0.f);
        if (row0 + r < NN)
            v = *reinterpret_cast<const float4*>(&node[(long)(row0 + r) * H + c]);
        *reinterpret_cast<float4*>(&sB[r * H + c]) = v;
    }
    __syncthreads();

    const int tc = t & 63;
    const int tr = t >> 6;
    const int c0 = tc * 4;
    const int r0 = tr * 8;

    // layer 1: h1 = silu(node @ W1), K = 128 — result kept in acc registers
    float acc[8][4];
#pragma unroll
    for (int r = 0; r < 8; ++r)
#pragma unroll
        for (int c = 0; c < 4; ++c) acc[r][c] = 0.f;

    for (int k = 0; k < H; k += 4) {
        float a[8][4];
#pragma unroll
        for (int r = 0; r < 8; ++r) {
            const float4 v = *reinterpret_cast<const float4*>(&sB[(r0 + r) * H + k]);
            a[r][0] = v.x; a[r][1] = v.y; a[r][2] = v.z; a[r][3] = v.w;
        }
#pragma unroll
        for (int kk = 0; kk < 4; ++kk) {
            const float4 w = *reinterpret_cast<const float4*>(&W1[(k + kk) * OE + c0]);
#pragma unroll
            for (int r = 0; r < 8; ++r) {
                const float av = a[r][kk];
                acc[r][0] += av * w.x; acc[r][1] += av * w.y;
                acc[r][2] += av * w.z; acc[r][3] += av * w.w;
            }
        }
    }
    __syncthreads();   // all sN reads done; safe to overwrite as sH
#pragma unroll
    for (int r = 0; r < 8; ++r)
#pragma unroll
        for (int c = 0; c < 4; ++c)
            sB[(r0 + r) * OE + c0 + c] = silu(acc[r][c]);
    __syncthreads();

    // layer 2: h2 = silu(h1 @ W2 + b2), K = 256, W3 fused
    float acc2[8][4];
#pragma unroll
    for (int r = 0; r < 8; ++r)
#pragma unroll
        for (int c = 0; c < 4; ++c) acc2[r][c] = 0.f;

    for (int k = 0; k < OE; k += 4) {
        float a[8][4];
#pragma unroll
        for (int r = 0; r < 8; ++r) {
            const float4 v = *reinterpret_cast<const float4*>(&sB[(r0 + r) * OE + k]);
            a[r][0] = v.x; a[r][1] = v.y; a[r][2] = v.z; a[r][3] = v.w;
        }
#pragma unroll
        for (int kk = 0; kk < 4; ++kk) {
            const float4 w = *reinterpret_cast<const float4*>(&W2[(k + kk) * OE + c0]);
#pragma unroll
            for (int r = 0; r < 8; ++r) {
                const float av = a[r][kk];
                acc2[r][0] += av * w.x; acc2[r][1] += av * w.y;
                acc2[r][2] += av * w.z; acc2[r][3] += av * w.w;
            }
        }
    }

    const float4 bb = *reinterpret_cast<const float4*>(&b2[c0]);
    const float4 w3 = *reinterpret_cast<const float4*>(&W3[c0]);
    float part[8];
#pragma unroll
    for (int r = 0; r < 8; ++r) {
        part[r] = silu(acc2[r][0] + bb.x) * w3.x
                + silu(acc2[r][1] + bb.y) * w3.y
                + silu(acc2[r][2] + bb.z) * w3.z
                + silu(acc2[r][3] + bb.w) * w3.w;
    }
#pragma unroll
    for (int r = 0; r < 8; ++r) {
        float p = part[r];
#pragma unroll
        for (int off = 32; off > 0; off >>= 1)
            p += __shfl_down(p, off, 64);
        part[r] = p;
    }
    if (tc == 0) {
#pragma unroll
        for (int r = 0; r < 8; ++r) {
            const int row = row0 + r0 + r;
            if (row < NN) out[row] = part[r];
        }
    }
}

extern "C" void kernel_launch(void* const* d_in, const int* in_sizes, int n_in,
                              void* d_out, int out_size, void* d_ws, size_t ws_size,
                              hipStream_t stream) {
    const float* x   = (const float*)d_in[0];
    const float* pb  = (const float*)d_in[1];
    const void*  idx = d_in[2];          // int32 or int64 — detected per wave
    // d_in[3] = num_nodes scalar (compile-time constant NN)
    const float* Wp  = (const float*)d_in[4];
    const float* W1  = (const float*)d_in[5];
    const float* W2  = (const float*)d_in[6];
    const float* b2  = (const float*)d_in[7];
    const float* W3  = (const float*)d_in[8];
    float* out = (float*)d_out;

    char* w = (char*)d_ws;
    float* node = (float*)(w + OFF_NODE);
    int*   cnt  = (int*)(w + OFF_CNT);
    int*   ovc  = (int*)(w + OFF_OVC);
    int*   ovf  = (int*)(w + OFF_OVF);
    int*   eid  = (int*)(w + OFF_EID);

    int cap = CAPMAX;
    if (ws_size > OFF_EID) {
        const size_t fit = (ws_size - OFF_EID) / ((size_t)NN * sizeof(int));
        if (fit < (size_t)cap) cap = (int)fit;
    }
    if (cap < 1) cap = 1;

    hipMemsetAsync(w + OFF_CNT, 0, 200192 + 256, stream);  // cnt + ovc
    slot_fill_kernel<<<E / 256, 256, 0, stream>>>(idx, cap, cnt, ovc, ovf, eid);
    gather_kernel<<<NN / 4, 256, 0, stream>>>(x, pb, cnt, eid, cap, Wp, node);
    ovf_apply_kernel<<<1, 256, 0, stream>>>(x, pb, idx, ovc, ovf, Wp, node);
    mlp_kernel<<<(NN + 31) / 32, 256, 0, stream>>>(node, W1, W2, b2, W3, out);
}